// Round 8
// baseline (179.726 us; speedup 1.0000x reference)
//
#include <hip/hip_runtime.h>
#include <hip/hip_bf16.h>

// DiagWinAttention: nw=4096, N=64 tokens, E=96 = 6 heads x 16. fp32 I/O.
// R8 = R7 (768-thread blocks, 2 windows side-by-side, 24 waves/CU) with the
// live set trimmed under the 85-VGPR budget implied by 55KB LDS:
//  - X written per row-tile (accumulator 16->4 VGPRs at the attention peak)
//  - LN strip re-read from LDS instead of held across barriers (-16)
//  - W fragments loaded after LN partials (-13 across attention)
// Spill tripwire: WRITE_SIZE must be exactly 98304 KB.

typedef short v4s __attribute__((ext_vector_type(4)));
typedef float v4f __attribute__((ext_vector_type(4)));

#define MFMA16(A, B, C) __builtin_amdgcn_mfma_f32_16x16x16bf16_1k(A, B, C, 0, 0, 0)

static __device__ __forceinline__ ushort f2b(float x) {
  union { __hip_bfloat16 h; ushort u; } c; c.h = __float2bfloat16(x); return c.u;
}
static __device__ __forceinline__ float b2f(ushort u) {
  union { ushort u; __hip_bfloat16 h; } c; c.u = u; return __bfloat162float(c.h);
}

#define SMS 68      // mask LDS row stride (bf16)
#define SXS 100     // X row stride (bf16); also fp32 Y stride in reuse
#define SBS 228     // bias table per-head stride (fp32)
#define LOG2E 1.4426950408889634f

__global__ __launch_bounds__(768, 6)
void winattn_kernel(const float* __restrict__ gQ, const float* __restrict__ gK,
                    const float* __restrict__ gV, const float* __restrict__ gM,
                    const float* __restrict__ gBT, const float* __restrict__ gGa,
                    const float* __restrict__ gBe, const float* __restrict__ gW,
                    const float* __restrict__ gPb, float* __restrict__ gO)
{
  __shared__ __align__(16) ushort sM[2][64 * SMS]; // 17408 B mask*log2e
  __shared__ __align__(16) ushort sX[2][64 * SXS]; // 25600 B X -> Xn -> fp32 Y
  __shared__ float sB[6 * SBS];                    //  5472 B bias tables*log2e
  __shared__ float sPS[2][64 * 13];                //  6656 B LN partials
  // total 55136 B -> 2 blocks/CU, 24 waves/CU

  const int tid   = threadIdx.x;
  const int wave  = tid >> 6;          // 0..11
  const int win   = wave >= 6;         // which of the 2 windows
  const int hw    = wave - 6 * win;    // head 0..5
  const int lane  = tid & 63;
  const int l15   = lane & 15;
  const int g     = lane >> 4;
  const int ctid  = tid - 384 * win;   // 0..383 within window group
  const unsigned base = ((unsigned)blockIdx.x * 2 + win) * 6144u;

  // ---- V fragments (B-operand): vf[kk] reg j = V[16kk+4g+j][16*hw+l15] ----
  v4s vf[4];
  {
    const float* vp = gV + base + 16 * hw + l15;
    #pragma unroll
    for (int kk = 0; kk < 4; ++kk) {
      float a0 = vp[(16 * kk + 4 * g + 0) * 96];
      float a1 = vp[(16 * kk + 4 * g + 1) * 96];
      float a2 = vp[(16 * kk + 4 * g + 2) * 96];
      float a3 = vp[(16 * kk + 4 * g + 3) * 96];
      v4s t; t[0] = (short)f2b(a0); t[1] = (short)f2b(a1);
      t[2] = (short)f2b(a2); t[3] = (short)f2b(a3);
      vf[kk] = t;
    }
  }

  // ---- Q,K fragments direct from global (A-operand rows) ----
  v4s aq[4], bk[4];
  {
    const float QS = 0.25f * LOG2E;              // scale * log2e folded into Q
    const float* qp = gQ + base + 16 * hw + 4 * g;
    const float* kp = gK + base + 16 * hw + 4 * g;
    #pragma unroll
    for (int t = 0; t < 4; ++t) {
      float4 qv = *(const float4*)(qp + (16 * t + l15) * 96);
      float4 kv = *(const float4*)(kp + (16 * t + l15) * 96);
      v4s a; a[0] = (short)f2b(qv.x * QS); a[1] = (short)f2b(qv.y * QS);
      a[2] = (short)f2b(qv.z * QS); a[3] = (short)f2b(qv.w * QS);
      aq[t] = a;
      v4s b; b[0] = (short)f2b(kv.x); b[1] = (short)f2b(kv.y);
      b[2] = (short)f2b(kv.z); b[3] = (short)f2b(kv.w);
      bk[t] = b;
    }
  }

  // ---- mask -> LDS (bf16, * log2e); each window's 384 threads stage theirs ----
  {
    const float4* m4 = (const float4*)(gM + ((size_t)blockIdx.x * 2 + win) * 4096);
    ushort* sMw = sM[win];
    #pragma unroll
    for (int i = 0; i < 3; ++i) {
      const int idx = ctid + i * 384;
      if (idx < 1024) {
        const int r = idx >> 4, c0 = (idx & 15) * 4;
        float4 a = m4[idx];
        ushort4 u;
        u.x = f2b(a.x * LOG2E); u.y = f2b(a.y * LOG2E);
        u.z = f2b(a.z * LOG2E); u.w = f2b(a.w * LOG2E);
        *(ushort4*)&sMw[r * SMS + c0] = u;
      }
    }
  }
  // ---- bias table -> LDS (fp32, * log2e, per-head layout) ----
  for (int i = tid; i < 1350; i += 768) {
    const int idx = i / 6, h = i - 6 * idx;
    sB[h * SBS + idx] = gBT[i] * LOG2E;
  }
  __syncthreads();

  // ---- fused attention: per row-tile QK^T -> softmax -> PV -> X write ----
  const float* bh = &sB[hw * SBS];
  const int bb = ((l15 >> 3) - (g >> 1)) * 15 + (l15 & 7) - 4 * (g & 1) + 112;
  const ushort* sMw = sM[win];
  ushort* sXw = sX[win];
  const float* qr = gQ + base + 16 * hw + l15;   // residual column

  #pragma unroll
  for (int rt = 0; rt < 4; ++rt) {
    v4f acc[4];
    #pragma unroll
    for (int ct = 0; ct < 4; ++ct) {
      ushort4 u = *(const ushort4*)&sMw[(16 * rt + l15) * SMS + 16 * ct + 4 * g];
      const int b0 = bb + 30 * (rt - ct);
      v4f ini = {bh[b0 - 0] + b2f(u.x), bh[b0 - 1] + b2f(u.y),
                 bh[b0 - 2] + b2f(u.z), bh[b0 - 3] + b2f(u.w)};
      acc[ct] = ini;
    }
    #pragma unroll
    for (int ct = 0; ct < 4; ++ct) acc[ct] = MFMA16(bk[ct], aq[rt], acc[ct]);

    float s = 0.f;
    #pragma unroll
    for (int ct = 0; ct < 4; ++ct) {
      float e0 = exp2f(acc[ct][0]);
      float e1 = exp2f(acc[ct][1]);
      float e2 = exp2f(acc[ct][2]);
      float e3 = exp2f(acc[ct][3]);
      v4f e = {e0, e1, e2, e3};
      acc[ct] = e;
      s += (e0 + e1) + (e2 + e3);
    }
    s += __shfl_xor(s, 16, 64);
    s += __shfl_xor(s, 32, 64);
    const float r = __builtin_amdgcn_rcpf(s);
    v4s pa[4];
    #pragma unroll
    for (int ct = 0; ct < 4; ++ct) {
      v4s t;
      t[0] = (short)f2b(acc[ct][0] * r); t[1] = (short)f2b(acc[ct][1] * r);
      t[2] = (short)f2b(acc[ct][2] * r); t[3] = (short)f2b(acc[ct][3] * r);
      pa[ct] = t;
    }
    v4f oa = {0.f, 0.f, 0.f, 0.f};
    #pragma unroll
    for (int ct = 0; ct < 4; ++ct) oa = MFMA16(pa[ct], vf[ct], oa);

    // residual + X write for this row-tile (rows 16rt+4g+rg, col 16hw+l15)
    #pragma unroll
    for (int rg = 0; rg < 4; ++rg) {
      const int row = 16 * rt + 4 * g + rg;
      sXw[row * SXS + 16 * hw + l15] = f2b(oa[rg] + 0.25f * qr[row * 96]);
    }
  }
  __syncthreads();

  // ---- LN partials: row = lane, strip = head ----
  float* sPSw = sPS[win];
  {
    const ushort* xr = &sXw[lane * SXS + 16 * hw];
    float s1 = 0.f, s2 = 0.f;
    #pragma unroll
    for (int i = 0; i < 4; ++i) {
      ushort4 u = *(const ushort4*)&xr[i * 4];
      float x0 = b2f(u.x), x1 = b2f(u.y), x2 = b2f(u.z), x3 = b2f(u.w);
      s1 += x0 + x1 + x2 + x3;
      s2 += x0 * x0 + x1 * x1 + x2 * x2 + x3 * x3;
    }
    sPSw[lane * 13 + 2 * hw + 0] = s1;
    sPSw[lane * 13 + 2 * hw + 1] = s2;
  }

  // ---- W fragments + proj bias (issued here; complete during LN) ----
  const int oc = 16 * hw + l15;
  v4s wfr[6];
  #pragma unroll
  for (int kk = 0; kk < 6; ++kk) {
    float4 wv = *(const float4*)(gW + oc * 96 + kk * 16 + 4 * g);
    v4s t; t[0] = (short)f2b(wv.x); t[1] = (short)f2b(wv.y);
    t[2] = (short)f2b(wv.z); t[3] = (short)f2b(wv.w);
    wfr[kk] = t;
  }
  const float pb = gPb[oc];
  __syncthreads();

  // ---- LN normalize (strip re-read from LDS, in-place) ----
  {
    float s1 = 0.f, s2 = 0.f;
    #pragma unroll
    for (int t = 0; t < 6; ++t) {
      s1 += sPSw[lane * 13 + 2 * t];
      s2 += sPSw[lane * 13 + 2 * t + 1];
    }
    const float mu  = s1 * (1.f / 96.f);
    const float var = s2 * (1.f / 96.f) - mu * mu;
    const float rsig = __builtin_amdgcn_rsqf(var + 1e-5f);
    const float* gp = gGa + 16 * hw;
    const float* bp = gBe + 16 * hw;
    ushort* xr = &sXw[lane * SXS + 16 * hw];
    #pragma unroll
    for (int i = 0; i < 4; ++i) {
      ushort4 u = *(const ushort4*)&xr[i * 4];
      ushort4 o;
      o.x = f2b((b2f(u.x) - mu) * rsig * gp[4 * i + 0] + bp[4 * i + 0]);
      o.y = f2b((b2f(u.y) - mu) * rsig * gp[4 * i + 1] + bp[4 * i + 1]);
      o.z = f2b((b2f(u.z) - mu) * rsig * gp[4 * i + 2] + bp[4 * i + 2]);
      o.w = f2b((b2f(u.w) - mu) * rsig * gp[4 * i + 3] + bp[4 * i + 3]);
      *(ushort4*)&xr[i * 4] = o;
    }
  }
  __syncthreads();

  // ---- projection: Y = Xn @ W^T + b ----
  v4f ya[4];
  #pragma unroll
  for (int mt = 0; mt < 4; ++mt) { v4f z = {0.f, 0.f, 0.f, 0.f}; ya[mt] = z; }
  #pragma unroll
  for (int kk = 0; kk < 6; ++kk)
    #pragma unroll
    for (int mt = 0; mt < 4; ++mt) {
      v4s xa = *(const v4s*)&sXw[(16 * mt + l15) * SXS + 16 * kk + 4 * g];
      ya[mt] = MFMA16(xa, wfr[kk], ya[mt]);
    }

  // ---- staged coalesced output: two 32-row halves through LDS (stride 100) ----
  __syncthreads();                       // all proj LDS reads done
  float* sY = (float*)sXw;               // [32][SXS] fp32 = 12800 B
  float4* o4 = (float4*)(gO + base);
  #pragma unroll
  for (int mt = 0; mt < 2; ++mt)
    #pragma unroll
    for (int rg = 0; rg < 4; ++rg)
      sY[(16 * mt + 4 * g + rg) * SXS + oc] = ya[mt][rg] + pb;
  __syncthreads();
  #pragma unroll
  for (int i = 0; i < 2; ++i) {
    const int idx = ctid + i * 384;
    const int r = idx / 24, c = idx % 24;
    o4[idx] = *(const float4*)&sY[r * SXS + c * 4];
  }
  __syncthreads();
  #pragma unroll
  for (int mt = 2; mt < 4; ++mt)
    #pragma unroll
    for (int rg = 0; rg < 4; ++rg)
      sY[(16 * (mt - 2) + 4 * g + rg) * SXS + oc] = ya[mt][rg] + pb;
  __syncthreads();
  #pragma unroll
  for (int i = 0; i < 2; ++i) {
    const int idx = ctid + i * 384;
    const int r = idx / 24, c = idx % 24;
    o4[768 + idx] = *(const float4*)&sY[r * SXS + c * 4];
  }
}

extern "C" void kernel_launch(void* const* d_in, const int* in_sizes, int n_in,
                              void* d_out, int out_size, void* d_ws, size_t ws_size,
                              hipStream_t stream) {
  (void)in_sizes; (void)n_in; (void)out_size; (void)d_ws; (void)ws_size;
  winattn_kernel<<<dim3(2048), dim3(768), 0, stream>>>(
      (const float*)d_in[0], (const float*)d_in[1], (const float*)d_in[2],
      (const float*)d_in[3], (const float*)d_in[4], (const float*)d_in[5],
      (const float*)d_in[6], (const float*)d_in[7], (const float*)d_in[8],
      (float*)d_out);
}

// Round 9
// 138.629 us; speedup vs baseline: 1.2965x; 1.2965x over previous
//
#include <hip/hip_runtime.h>
#include <hip/hip_bf16.h>

// DiagWinAttention: nw=4096, N=64 tokens, E=96 = 6 heads x 16. fp32 I/O.
// R9 = R5 shell (384 thr, 1 window/block, launch_bounds(384,5) -- the proven
// no-spill point) with arch-VGPR liveness cuts:
//  - normalize-after-PV: pa kept unnormalized bf16; only one acc[4] live
//    (serial ct tiles); r applied to O via 4 shfl per row-tile
//  - per-row-tile fused X write (no oa[4][4] array)
// Register model from R4-R8: budget = 512/waves_per_EU, split ~50/50
// arch/acc; spill iff arch demand > budget/2. Tripwire: WRITE_SIZE == 98304.

typedef short v4s __attribute__((ext_vector_type(4)));
typedef float v4f __attribute__((ext_vector_type(4)));

#define MFMA16(A, B, C) __builtin_amdgcn_mfma_f32_16x16x16bf16_1k(A, B, C, 0, 0, 0)

static __device__ __forceinline__ ushort f2b(float x) {
  union { __hip_bfloat16 h; ushort u; } c; c.h = __float2bfloat16(x); return c.u;
}
static __device__ __forceinline__ float b2f(ushort u) {
  union { ushort u; __hip_bfloat16 h; } c; c.u = u; return __bfloat162float(c.h);
}

#define SMS 68      // mask LDS row stride (bf16)
#define SXS 100     // X row stride (bf16); also fp32 Y stride in reuse
#define SBS 228     // bias table per-head stride (fp32)
#define LOG2E 1.4426950408889634f

__global__ __launch_bounds__(384, 5)
void winattn_kernel(const float* __restrict__ gQ, const float* __restrict__ gK,
                    const float* __restrict__ gV, const float* __restrict__ gM,
                    const float* __restrict__ gBT, const float* __restrict__ gGa,
                    const float* __restrict__ gBe, const float* __restrict__ gW,
                    const float* __restrict__ gPb, float* __restrict__ gO)
{
  __shared__ __align__(16) ushort sM[64 * SMS];  //  8704 B mask * log2e (bf16)
  __shared__ __align__(16) ushort sX[64 * SXS];  // 12800 B X -> Xn -> fp32 Y
  __shared__ float sB[6 * SBS];                  //  5472 B bias tables * log2e
  __shared__ float sPS[64 * 13];                 //  3328 B LN partials
  // total 30304 B

  const int tid  = threadIdx.x;
  const int w    = blockIdx.x;
  const int wave = tid >> 6;         // head
  const int lane = tid & 63;
  const int l15  = lane & 15;
  const int g    = lane >> 4;
  const size_t base = (size_t)w * 6144;

  // ---- mask -> LDS first (the first barrier gates only sM/sB) ----
  {
    const float4* m4 = (const float4*)(gM + (size_t)w * 4096);
    #pragma unroll
    for (int i = 0; i < 3; ++i) {
      const int idx = tid + i * 384;
      if (idx < 1024) {
        const int r = idx >> 4, c0 = (idx & 15) * 4;
        float4 a = m4[idx];
        ushort4 u;
        u.x = f2b(a.x * LOG2E); u.y = f2b(a.y * LOG2E);
        u.z = f2b(a.z * LOG2E); u.w = f2b(a.w * LOG2E);
        *(ushort4*)&sM[r * SMS + c0] = u;
      }
    }
  }
  // ---- bias table -> LDS (fp32, * log2e, per-head layout) ----
  for (int i = tid; i < 1350; i += 384) {
    const int idx = i / 6, h = i - 6 * idx;
    sB[h * SBS + idx] = gBT[i] * LOG2E;
  }

  // ---- V fragments (B-operand): vf[kk] reg j = V[16kk+4g+j][16*wave+l15] ----
  v4s vf[4];
  {
    const float* vp = gV + base + 16 * wave + l15;
    #pragma unroll
    for (int kk = 0; kk < 4; ++kk) {
      float a0 = vp[(16 * kk + 4 * g + 0) * 96];
      float a1 = vp[(16 * kk + 4 * g + 1) * 96];
      float a2 = vp[(16 * kk + 4 * g + 2) * 96];
      float a3 = vp[(16 * kk + 4 * g + 3) * 96];
      v4s t; t[0] = (short)f2b(a0); t[1] = (short)f2b(a1);
      t[2] = (short)f2b(a2); t[3] = (short)f2b(a3);
      vf[kk] = t;
    }
  }

  // ---- Q,K fragments direct from global (A-operand rows) ----
  v4s aq[4], bk[4];
  {
    const float QS = 0.25f * LOG2E;              // scale * log2e folded into Q
    const float* qp = gQ + base + 16 * wave + 4 * g;
    const float* kp = gK + base + 16 * wave + 4 * g;
    #pragma unroll
    for (int t = 0; t < 4; ++t) {
      float4 qv = *(const float4*)(qp + (16 * t + l15) * 96);
      float4 kv = *(const float4*)(kp + (16 * t + l15) * 96);
      v4s a; a[0] = (short)f2b(qv.x * QS); a[1] = (short)f2b(qv.y * QS);
      a[2] = (short)f2b(qv.z * QS); a[3] = (short)f2b(qv.w * QS);
      aq[t] = a;
      v4s b; b[0] = (short)f2b(kv.x); b[1] = (short)f2b(kv.y);
      b[2] = (short)f2b(kv.z); b[3] = (short)f2b(kv.w);
      bk[t] = b;
    }
  }
  __syncthreads();

  // ---- fused attention: per row-tile, serial ct: QK^T -> exp2 -> bf16 pa
  //      (unnormalized); after PV scale O by r (P linear in V) ----
  const float* bh = &sB[wave * SBS];
  const int bb = ((l15 >> 3) - (g >> 1)) * 15 + (l15 & 7) - 4 * (g & 1) + 112;
  const float* qr = gQ + base + 16 * wave + l15;   // residual column

  #pragma unroll
  for (int rt = 0; rt < 4; ++rt) {
    float s = 0.f;
    v4s pa[4];
    #pragma unroll
    for (int ct = 0; ct < 4; ++ct) {
      ushort4 u = *(const ushort4*)&sM[(16 * rt + l15) * SMS + 16 * ct + 4 * g];
      const int b0 = bb + 30 * (rt - ct);
      v4f acc = {bh[b0 - 0] + b2f(u.x), bh[b0 - 1] + b2f(u.y),
                 bh[b0 - 2] + b2f(u.z), bh[b0 - 3] + b2f(u.w)};
      acc = MFMA16(bk[ct], aq[rt], acc);
      float e0 = exp2f(acc[0]);
      float e1 = exp2f(acc[1]);
      float e2 = exp2f(acc[2]);
      float e3 = exp2f(acc[3]);
      s += (e0 + e1) + (e2 + e3);
      v4s t;
      t[0] = (short)f2b(e0); t[1] = (short)f2b(e1);
      t[2] = (short)f2b(e2); t[3] = (short)f2b(e3);
      pa[ct] = t;
    }
    s += __shfl_xor(s, 16, 64);
    s += __shfl_xor(s, 32, 64);
    const float r = __builtin_amdgcn_rcpf(s);   // per row 16rt+l15

    v4f oa = {0.f, 0.f, 0.f, 0.f};
    #pragma unroll
    for (int ct = 0; ct < 4; ++ct) oa = MFMA16(pa[ct], vf[ct], oa);

    // O row = 16rt+4g+rg needs r from lane with l15 == 4g+rg
    #pragma unroll
    for (int rg = 0; rg < 4; ++rg) {
      const float rr = __shfl(r, 4 * g + rg, 64);
      const int row = 16 * rt + 4 * g + rg;
      sX[row * SXS + 16 * wave + l15] = f2b(oa[rg] * rr + 0.25f * qr[row * 96]);
    }
  }
  __syncthreads();

  // ---- LN partials: row = lane, strip = head ----
  {
    const ushort* xr = &sX[lane * SXS + 16 * wave];
    float s1 = 0.f, s2 = 0.f;
    #pragma unroll
    for (int i = 0; i < 4; ++i) {
      ushort4 u = *(const ushort4*)&xr[i * 4];
      float x0 = b2f(u.x), x1 = b2f(u.y), x2 = b2f(u.z), x3 = b2f(u.w);
      s1 += x0 + x1 + x2 + x3;
      s2 += x0 * x0 + x1 * x1 + x2 * x2 + x3 * x3;
    }
    sPS[lane * 13 + 2 * wave + 0] = s1;
    sPS[lane * 13 + 2 * wave + 1] = s2;
  }

  // ---- W fragments + proj bias (issued here; complete during LN) ----
  const int oc = 16 * wave + l15;
  v4s wfr[6];
  #pragma unroll
  for (int kk = 0; kk < 6; ++kk) {
    float4 wv = *(const float4*)(gW + oc * 96 + kk * 16 + 4 * g);
    v4s t; t[0] = (short)f2b(wv.x); t[1] = (short)f2b(wv.y);
    t[2] = (short)f2b(wv.z); t[3] = (short)f2b(wv.w);
    wfr[kk] = t;
  }
  const float pb = gPb[oc];
  __syncthreads();

  // ---- LN normalize (strip re-read from LDS, in-place) ----
  {
    float s1 = 0.f, s2 = 0.f;
    #pragma unroll
    for (int t = 0; t < 6; ++t) {
      s1 += sPS[lane * 13 + 2 * t];
      s2 += sPS[lane * 13 + 2 * t + 1];
    }
    const float mu  = s1 * (1.f / 96.f);
    const float var = s2 * (1.f / 96.f) - mu * mu;
    const float rsig = __builtin_amdgcn_rsqf(var + 1e-5f);
    const float* gp = gGa + 16 * wave;
    const float* bp = gBe + 16 * wave;
    ushort* xr = &sX[lane * SXS + 16 * wave];
    #pragma unroll
    for (int i = 0; i < 4; ++i) {
      ushort4 u = *(const ushort4*)&xr[i * 4];
      ushort4 o;
      o.x = f2b((b2f(u.x) - mu) * rsig * gp[4 * i + 0] + bp[4 * i + 0]);
      o.y = f2b((b2f(u.y) - mu) * rsig * gp[4 * i + 1] + bp[4 * i + 1]);
      o.z = f2b((b2f(u.z) - mu) * rsig * gp[4 * i + 2] + bp[4 * i + 2]);
      o.w = f2b((b2f(u.w) - mu) * rsig * gp[4 * i + 3] + bp[4 * i + 3]);
      *(ushort4*)&xr[i * 4] = o;
    }
  }
  __syncthreads();

  // ---- projection: Y = Xn @ W^T + b ----
  v4f ya[4];
  #pragma unroll
  for (int mt = 0; mt < 4; ++mt) { v4f z = {0.f, 0.f, 0.f, 0.f}; ya[mt] = z; }
  #pragma unroll
  for (int kk = 0; kk < 6; ++kk)
    #pragma unroll
    for (int mt = 0; mt < 4; ++mt) {
      v4s xa = *(const v4s*)&sX[(16 * mt + l15) * SXS + 16 * kk + 4 * g];
      ya[mt] = MFMA16(xa, wfr[kk], ya[mt]);
    }

  // ---- staged coalesced output: two 32-row halves through LDS (stride 100) ----
  __syncthreads();                       // all proj LDS reads done
  float* sY = (float*)sX;                // [32][SXS] fp32 = 12800 B
  float4* o4 = (float4*)(gO + base);
  #pragma unroll
  for (int mt = 0; mt < 2; ++mt)
    #pragma unroll
    for (int rg = 0; rg < 4; ++rg)
      sY[(16 * mt + 4 * g + rg) * SXS + oc] = ya[mt][rg] + pb;
  __syncthreads();
  #pragma unroll
  for (int i = 0; i < 2; ++i) {
    const int idx = tid + i * 384;
    const int r = idx / 24, c = idx % 24;
    o4[idx] = *(const float4*)&sY[r * SXS + c * 4];
  }
  __syncthreads();
  #pragma unroll
  for (int mt = 2; mt < 4; ++mt)
    #pragma unroll
    for (int rg = 0; rg < 4; ++rg)
      sY[(16 * (mt - 2) + 4 * g + rg) * SXS + oc] = ya[mt][rg] + pb;
  __syncthreads();
  #pragma unroll
  for (int i = 0; i < 2; ++i) {
    const int idx = tid + i * 384;
    const int r = idx / 24, c = idx % 24;
    o4[768 + idx] = *(const float4*)&sY[r * SXS + c * 4];
  }
}

extern "C" void kernel_launch(void* const* d_in, const int* in_sizes, int n_in,
                              void* d_out, int out_size, void* d_ws, size_t ws_size,
                              hipStream_t stream) {
  (void)in_sizes; (void)n_in; (void)out_size; (void)d_ws; (void)ws_size;
  winattn_kernel<<<dim3(4096), dim3(384), 0, stream>>>(
      (const float*)d_in[0], (const float*)d_in[1], (const float*)d_in[2],
      (const float*)d_in[3], (const float*)d_in[4], (const float*)d_in[5],
      (const float*)d_in[6], (const float*)d_in[7], (const float*)d_in[8],
      (float*)d_out);
}